// Round 1
// baseline (59.528 us; speedup 1.0000x reference)
//
#include <hip/hip_runtime.h>
#include <math.h>

#define NB 32
#define NT 1024
#define NK 12
#define NC 64
#define NS 100

// ---------------------------------------------------------------------------
// ws layout: double acc[4] (0=ll_sum, 1=mu_reg, 2=L_reg, 3=pad), int present[100]
// ---------------------------------------------------------------------------

__global__ __launch_bounds__(128) void init_kernel(double* __restrict__ acc,
                                                   int* __restrict__ present) {
  int tid = threadIdx.x;
  if (tid < 4) acc[tid] = 0.0;
  if (tid < NS) present[tid] = 0;
}

// One thread per (b,k,t). Forward substitution z = L^{-1}(x_t - mu), fully
// unrolled so z[] stays in VGPRs. L reads are block-uniform -> s_load (SMEM
// pipe, overlaps the VALU FMA chain). gamma-weighting + block reduce fused.
__global__ __launch_bounds__(256) void solve_kernel(
    const float* __restrict__ data,      // (B,T,C)
    const float* __restrict__ mu_subj,   // (S,K,C)
    const float* __restrict__ L_subj,    // (S,K,C,C)
    const float* __restrict__ gamma,     // (B,T,K)
    const int*   __restrict__ sids,      // (B,1)
    double*      __restrict__ acc,
    int*         __restrict__ present) {
  // XCD-aware decode: all 48 (k,tile) blocks of one b land on the same XCD
  // (dispatch round-robins blockIdx % 8 across the 8 XCDs).
  int blk  = blockIdx.x;
  int x    = blk & 7;
  int r    = blk >> 3;              // [0,192)
  int b    = (r / 48) * 8 + x;      // [0,32)
  int kt   = r % 48;
  int k    = kt >> 2;               // [0,12)
  int tile = kt & 3;                // [0,4)
  int tid  = threadIdx.x;
  int lane = tid & 63;
  int t    = tile * 256 + tid;

  int sid = __builtin_amdgcn_readfirstlane(sids[b]);
  if (tid == 0 && k == 0 && tile == 0) present[sid] = 1;

  const float* __restrict__ Lb = L_subj + (size_t)(sid * NK + k) * (NC * NC);
  const float* __restrict__ mu = mu_subj + (size_t)(sid * NK + k) * NC;

  // logdet = sum log diag(L): lane-parallel + wave reduce (broadcast to all)
  float ld = __logf(Lb[lane * (NC + 1)]);
#pragma unroll
  for (int off = 1; off < 64; off <<= 1) ld += __shfl_xor(ld, off);

  // diff -> z[]
  float z[NC];
  const float4* dp =
      reinterpret_cast<const float4*>(data + ((size_t)b * NT + t) * NC);
#pragma unroll
  for (int i = 0; i < NC / 4; ++i) {
    float4 v = dp[i];
    z[4 * i + 0] = v.x - mu[4 * i + 0];
    z[4 * i + 1] = v.y - mu[4 * i + 1];
    z[4 * i + 2] = v.z - mu[4 * i + 2];
    z[4 * i + 3] = v.w - mu[4 * i + 3];
  }

  // forward substitution, quad = ||z||^2
  float quad = 0.0f;
#pragma unroll
  for (int c = 0; c < NC; ++c) {
    float a = z[c];
#pragma unroll
    for (int j = 0; j < c; ++j) a = fmaf(-Lb[c * NC + j], z[j], a);
    float zc = a * __builtin_amdgcn_rcpf(Lb[c * NC + c]);
    z[c] = zc;
    quad = fmaf(zc, zc, quad);
  }

  // weighted log-prob contribution (constant term folded into finalize)
  float g = gamma[((size_t)b * NT + t) * NK + k];
  float w = g * (-0.5f * quad - ld);

#pragma unroll
  for (int off = 1; off < 64; off <<= 1) w += __shfl_xor(w, off);

  __shared__ float red[4];
  if (lane == 0) red[tid >> 6] = w;
  __syncthreads();
  if (tid == 0) {
    float s = red[0] + red[1] + red[2] + red[3];
    atomicAdd(acc, (double)s);
  }
}

// One block per (s,k); skip absent subjects (block-uniform branch).
__global__ __launch_bounds__(256) void reg_kernel(
    const float* __restrict__ mu_pop,   // (K,C)
    const float* __restrict__ L_pop,    // (K,C,C)
    const float* __restrict__ mu_subj,  // (S,K,C)
    const float* __restrict__ L_subj,   // (S,K,C,C)
    const int*   __restrict__ present,
    double*      __restrict__ acc) {
  int s = blockIdx.x / NK;
  int k = blockIdx.x % NK;
  if (present[s] == 0) return;
  int tid = threadIdx.x;

  const float4* Ls =
      reinterpret_cast<const float4*>(L_subj + (size_t)(s * NK + k) * (NC * NC));
  const float4* Lp =
      reinterpret_cast<const float4*>(L_pop + (size_t)k * (NC * NC));
  float sl = 0.0f;
#pragma unroll
  for (int i = 0; i < 4; ++i) {
    int idx = tid + i * 256;
    float4 a = Ls[idx], p = Lp[idx];
    float dx = a.x - p.x, dy = a.y - p.y, dz = a.z - p.z, dw = a.w - p.w;
    sl += dx * dx + dy * dy + dz * dz + dw * dw;
  }
  float sm = 0.0f;
  if (tid < NC) {
    float d = mu_subj[(size_t)(s * NK + k) * NC + tid] - mu_pop[k * NC + tid];
    sm = d * d;
  }
#pragma unroll
  for (int off = 1; off < 64; off <<= 1) {
    sl += __shfl_xor(sl, off);
    sm += __shfl_xor(sm, off);
  }
  __shared__ float rl[4], rm[4];
  int lane = tid & 63;
  if (lane == 0) {
    rl[tid >> 6] = sl;
    rm[tid >> 6] = sm;
  }
  __syncthreads();
  if (tid == 0) {
    atomicAdd(acc + 1, (double)(rm[0] + rm[1] + rm[2] + rm[3]));
    atomicAdd(acc + 2, (double)(rl[0] + rl[1] + rl[2] + rl[3]));
  }
}

__global__ __launch_bounds__(64) void finalize_kernel(
    const double* __restrict__ acc, const int* __restrict__ present,
    float* __restrict__ out) {
  if (threadIdx.x == 0) {
    int cnt = 0;
    for (int s = 0; s < NS; ++s) cnt += present[s];
    double c0 = 0.5 * (double)NC * log(2.0 * M_PI);
    double ll = acc[0] / (double)NB - (double)NT * c0;
    double nll = -ll;
    double reg = (0.5 * acc[1] + 0.5 * acc[2]) * ((double)cnt / (double)NS);
    out[0] = (float)(nll + reg);
  }
}

extern "C" void kernel_launch(void* const* d_in, const int* in_sizes, int n_in,
                              void* d_out, int out_size, void* d_ws,
                              size_t ws_size, hipStream_t stream) {
  const float* data    = (const float*)d_in[0];
  const float* mu_pop  = (const float*)d_in[1];
  const float* L_pop   = (const float*)d_in[2];
  const float* mu_subj = (const float*)d_in[3];
  const float* L_subj  = (const float*)d_in[4];
  const float* gamma   = (const float*)d_in[5];
  const int*   sids    = (const int*)d_in[6];
  float* out = (float*)d_out;

  double* acc   = (double*)d_ws;
  int* present  = (int*)((char*)d_ws + 4 * sizeof(double));

  hipLaunchKernelGGL(init_kernel, dim3(1), dim3(128), 0, stream, acc, present);
  hipLaunchKernelGGL(solve_kernel, dim3(NB * NK * 4), dim3(256), 0, stream,
                     data, mu_subj, L_subj, gamma, sids, acc, present);
  hipLaunchKernelGGL(reg_kernel, dim3(NS * NK), dim3(256), 0, stream, mu_pop,
                     L_pop, mu_subj, L_subj, present, acc);
  hipLaunchKernelGGL(finalize_kernel, dim3(1), dim3(64), 0, stream, acc,
                     present, out);
}

// Round 2
// 55.931 us; speedup vs baseline: 1.0643x; 1.0643x over previous
//
#include <hip/hip_runtime.h>
#include <math.h>

#define NB 32
#define NT 1024
#define NK 12
#define NC 64
#define NS 100
#define SOLVE_BLOCKS (NB * NK * 4)  // 1536
#define REG_BLOCKS (NS * NK)        // 1200

// ---------------------------------------------------------------------------
// ws layout (floats): solve_part[1536] | mu_part[1200] | L_part[1200] | int present[100]
// ---------------------------------------------------------------------------

__global__ __launch_bounds__(128) void init_kernel(int* __restrict__ present) {
  int tid = threadIdx.x;
  if (tid < NS) present[tid] = 0;
}

// Fully-static forward substitution: template recursion over row index so the
// inner loop bound is a compile-time constant -> z[] indices all static ->
// z stays in VGPRs (no scratch). L reads are block-uniform -> s_load.
template <int C>
struct Row {
  static __device__ __forceinline__ void run(float (&z)[NC],
                                             const float* __restrict__ Lb,
                                             float& quad) {
    float a = z[C];
#pragma unroll
    for (int j = 0; j < C; ++j) a = fmaf(-Lb[C * NC + j], z[j], a);
    float zc = a * __builtin_amdgcn_rcpf(Lb[C * NC + C]);
    z[C] = zc;
    quad = fmaf(zc, zc, quad);
    Row<C + 1>::run(z, Lb, quad);
  }
};
template <>
struct Row<NC> {
  static __device__ __forceinline__ void run(float (&)[NC], const float*,
                                             float&) {}
};

// One thread per (b,k,t). Per-block partial written to ws (no atomics).
__global__ __launch_bounds__(256) void solve_kernel(
    const float* __restrict__ data,      // (B,T,C)
    const float* __restrict__ mu_subj,   // (S,K,C)
    const float* __restrict__ L_subj,    // (S,K,C,C)
    const float* __restrict__ gamma,     // (B,T,K)
    const int*   __restrict__ sids,      // (B,1)
    float*       __restrict__ solve_part,
    int*         __restrict__ present) {
  // XCD-aware decode: all 48 (k,tile) blocks of one b land on one XCD.
  int blk  = blockIdx.x;
  int x    = blk & 7;
  int r    = blk >> 3;          // [0,192)
  int b    = (r / 48) * 8 + x;  // [0,32)
  int kt   = r % 48;
  int k    = kt >> 2;           // [0,12)
  int tile = kt & 3;            // [0,4)
  int tid  = threadIdx.x;
  int lane = tid & 63;
  int t    = tile * 256 + tid;

  int sid = __builtin_amdgcn_readfirstlane(sids[b]);
  if (tid == 0 && k == 0 && tile == 0) present[sid] = 1;

  const float* __restrict__ Lb = L_subj + (size_t)(sid * NK + k) * (NC * NC);
  const float* __restrict__ mu = mu_subj + (size_t)(sid * NK + k) * NC;

  // logdet = sum log diag(L): lane-parallel + wave reduce
  float ld = __logf(Lb[lane * (NC + 1)]);
#pragma unroll
  for (int off = 1; off < 64; off <<= 1) ld += __shfl_xor(ld, off);

  // diff -> z[]
  float z[NC];
  const float4* dp =
      reinterpret_cast<const float4*>(data + ((size_t)b * NT + t) * NC);
#pragma unroll
  for (int i = 0; i < NC / 4; ++i) {
    float4 v = dp[i];
    z[4 * i + 0] = v.x - mu[4 * i + 0];
    z[4 * i + 1] = v.y - mu[4 * i + 1];
    z[4 * i + 2] = v.z - mu[4 * i + 2];
    z[4 * i + 3] = v.w - mu[4 * i + 3];
  }

  // forward substitution, quad = ||z||^2 (fully static)
  float quad = 0.0f;
  Row<0>::run(z, Lb, quad);

  // weighted log-prob contribution (constant term folded into finalize)
  float g = gamma[((size_t)b * NT + t) * NK + k];
  float w = g * (-0.5f * quad - ld);

#pragma unroll
  for (int off = 1; off < 64; off <<= 1) w += __shfl_xor(w, off);

  __shared__ float red[4];
  if (lane == 0) red[tid >> 6] = w;
  __syncthreads();
  if (tid == 0) solve_part[blockIdx.x] = red[0] + red[1] + red[2] + red[3];
}

// One block per (s,k); absent subjects write zero partials and exit.
__global__ __launch_bounds__(256) void reg_kernel(
    const float* __restrict__ mu_pop,   // (K,C)
    const float* __restrict__ L_pop,    // (K,C,C)
    const float* __restrict__ mu_subj,  // (S,K,C)
    const float* __restrict__ L_subj,   // (S,K,C,C)
    const int*   __restrict__ present,
    float*       __restrict__ mu_part,
    float*       __restrict__ L_part) {
  int bid = blockIdx.x;
  int s = bid / NK;
  int k = bid % NK;
  int tid = threadIdx.x;
  if (present[s] == 0) {
    if (tid == 0) {
      mu_part[bid] = 0.0f;
      L_part[bid] = 0.0f;
    }
    return;
  }

  const float4* Ls =
      reinterpret_cast<const float4*>(L_subj + (size_t)(s * NK + k) * (NC * NC));
  const float4* Lp =
      reinterpret_cast<const float4*>(L_pop + (size_t)k * (NC * NC));
  float sl = 0.0f;
#pragma unroll
  for (int i = 0; i < 4; ++i) {
    int idx = tid + i * 256;
    float4 a = Ls[idx], p = Lp[idx];
    float dx = a.x - p.x, dy = a.y - p.y, dz = a.z - p.z, dw = a.w - p.w;
    sl += dx * dx + dy * dy + dz * dz + dw * dw;
  }
  float sm = 0.0f;
  if (tid < NC) {
    float d = mu_subj[(size_t)(s * NK + k) * NC + tid] - mu_pop[k * NC + tid];
    sm = d * d;
  }
#pragma unroll
  for (int off = 1; off < 64; off <<= 1) {
    sl += __shfl_xor(sl, off);
    sm += __shfl_xor(sm, off);
  }
  __shared__ float rl[4], rm[4];
  int lane = tid & 63;
  if (lane == 0) {
    rl[tid >> 6] = sl;
    rm[tid >> 6] = sm;
  }
  __syncthreads();
  if (tid == 0) {
    mu_part[bid] = rm[0] + rm[1] + rm[2] + rm[3];
    L_part[bid] = rl[0] + rl[1] + rl[2] + rl[3];
  }
}

// Deterministic parallel reduce of all partials + final combine.
__global__ __launch_bounds__(256) void finalize_kernel(
    const float* __restrict__ solve_part, const float* __restrict__ mu_part,
    const float* __restrict__ L_part, const int* __restrict__ present,
    float* __restrict__ out) {
  int tid = threadIdx.x;
  double s_ll = 0.0, s_mu = 0.0, s_L = 0.0;
  for (int i = tid; i < SOLVE_BLOCKS; i += 256) s_ll += (double)solve_part[i];
  for (int i = tid; i < REG_BLOCKS; i += 256) {
    s_mu += (double)mu_part[i];
    s_L += (double)L_part[i];
  }
  int cnt = (tid < NS) ? present[tid] : 0;
#pragma unroll
  for (int off = 1; off < 64; off <<= 1) {
    s_ll += __shfl_xor(s_ll, off);
    s_mu += __shfl_xor(s_mu, off);
    s_L += __shfl_xor(s_L, off);
    cnt += __shfl_xor(cnt, off);
  }
  __shared__ double r0[4], r1[4], r2[4];
  __shared__ int r3[4];
  int lane = tid & 63;
  if (lane == 0) {
    r0[tid >> 6] = s_ll;
    r1[tid >> 6] = s_mu;
    r2[tid >> 6] = s_L;
    r3[tid >> 6] = cnt;
  }
  __syncthreads();
  if (tid == 0) {
    double ll_sum = r0[0] + r0[1] + r0[2] + r0[3];
    double mu_reg = r1[0] + r1[1] + r1[2] + r1[3];
    double L_reg = r2[0] + r2[1] + r2[2] + r2[3];
    int c = r3[0] + r3[1] + r3[2] + r3[3];
    double c0 = 0.5 * (double)NC * log(2.0 * M_PI);
    double ll = ll_sum / (double)NB - (double)NT * c0;
    double reg = (0.5 * mu_reg + 0.5 * L_reg) * ((double)c / (double)NS);
    out[0] = (float)(-ll + reg);
  }
}

extern "C" void kernel_launch(void* const* d_in, const int* in_sizes, int n_in,
                              void* d_out, int out_size, void* d_ws,
                              size_t ws_size, hipStream_t stream) {
  const float* data    = (const float*)d_in[0];
  const float* mu_pop  = (const float*)d_in[1];
  const float* L_pop   = (const float*)d_in[2];
  const float* mu_subj = (const float*)d_in[3];
  const float* L_subj  = (const float*)d_in[4];
  const float* gamma   = (const float*)d_in[5];
  const int*   sids    = (const int*)d_in[6];
  float* out = (float*)d_out;

  float* solve_part = (float*)d_ws;
  float* mu_part    = solve_part + SOLVE_BLOCKS;
  float* L_part     = mu_part + REG_BLOCKS;
  int*   present    = (int*)(L_part + REG_BLOCKS);

  hipLaunchKernelGGL(init_kernel, dim3(1), dim3(128), 0, stream, present);
  hipLaunchKernelGGL(solve_kernel, dim3(SOLVE_BLOCKS), dim3(256), 0, stream,
                     data, mu_subj, L_subj, gamma, sids, solve_part, present);
  hipLaunchKernelGGL(reg_kernel, dim3(REG_BLOCKS), dim3(256), 0, stream,
                     mu_pop, L_pop, mu_subj, L_subj, present, mu_part, L_part);
  hipLaunchKernelGGL(finalize_kernel, dim3(1), dim3(256), 0, stream,
                     solve_part, mu_part, L_part, present, out);
}

// Round 3
// 53.808 us; speedup vs baseline: 1.1063x; 1.0395x over previous
//
#include <hip/hip_runtime.h>
#include <math.h>

#define NB 32
#define NT 1024
#define NK 12
#define NC 64
#define NS 100
#define SOLVE_BLOCKS (NB * NK * 4)  // 1536
#define REG_BLOCKS (NS * NK)        // 1200

typedef float f32x16 __attribute__((ext_vector_type(16)));

// ---------------------------------------------------------------------------
// ws layout (floats): solve_part[1536] | mu_part[1200] | L_part[1200] | int present[100]
// ---------------------------------------------------------------------------

__global__ __launch_bounds__(128) void init_kernel(int* __restrict__ present) {
  int tid = threadIdx.x;
  if (tid < NS) present[tid] = 0;
}

// z held in 4 x ext_vector(16) float: SSA vector values, element access with
// compile-time indices -> guaranteed VGPR-resident (no alloca, no scratch).
// Template recursion keeps every index a compile-time constant.
template <int C>
struct Row {
  static __device__ __forceinline__ void run(f32x16& z0, f32x16& z1,
                                             f32x16& z2, f32x16& z3,
                                             const float* __restrict__ Lb,
                                             float& quad) {
    float a = (C < 16) ? z0[C & 15]
              : (C < 32) ? z1[C & 15]
              : (C < 48) ? z2[C & 15]
                         : z3[C & 15];
#pragma unroll
    for (int j = 0; j < C; ++j) {
      float zj = (j < 16) ? z0[j & 15]
                 : (j < 32) ? z1[j & 15]
                 : (j < 48) ? z2[j & 15]
                            : z3[j & 15];
      a = fmaf(-Lb[C * NC + j], zj, a);
    }
    float zc = a * __builtin_amdgcn_rcpf(Lb[C * NC + C]);
    if (C < 16) z0[C & 15] = zc;
    else if (C < 32) z1[C & 15] = zc;
    else if (C < 48) z2[C & 15] = zc;
    else z3[C & 15] = zc;
    quad = fmaf(zc, zc, quad);
    Row<C + 1>::run(z0, z1, z2, z3, Lb, quad);
  }
};
template <>
struct Row<NC> {
  static __device__ __forceinline__ void run(f32x16&, f32x16&, f32x16&,
                                             f32x16&, const float*, float&) {}
};

// One thread per (b,k,t). Per-block partial written to ws (no atomics).
__global__ __launch_bounds__(256) void solve_kernel(
    const float* __restrict__ data,      // (B,T,C)
    const float* __restrict__ mu_subj,   // (S,K,C)
    const float* __restrict__ L_subj,    // (S,K,C,C)
    const float* __restrict__ gamma,     // (B,T,K)
    const int*   __restrict__ sids,      // (B,1)
    float*       __restrict__ solve_part,
    int*         __restrict__ present) {
  // XCD-aware decode: all 48 (k,tile) blocks of one b land on one XCD.
  int blk  = blockIdx.x;
  int x    = blk & 7;
  int r    = blk >> 3;          // [0,192)
  int b    = (r / 48) * 8 + x;  // [0,32)
  int kt   = r % 48;
  int k    = kt >> 2;           // [0,12)
  int tile = kt & 3;            // [0,4)
  int tid  = threadIdx.x;
  int lane = tid & 63;
  int t    = tile * 256 + tid;

  int sid = __builtin_amdgcn_readfirstlane(sids[b]);
  if (tid == 0 && k == 0 && tile == 0) present[sid] = 1;

  const float* __restrict__ Lb = L_subj + (size_t)(sid * NK + k) * (NC * NC);
  const float* __restrict__ mu = mu_subj + (size_t)(sid * NK + k) * NC;

  // logdet = sum log diag(L): lane-parallel + wave reduce
  float ld = __logf(Lb[lane * (NC + 1)]);
#pragma unroll
  for (int off = 1; off < 64; off <<= 1) ld += __shfl_xor(ld, off);

  // diff -> z (register vectors)
  f32x16 z0, z1, z2, z3;
  const float4* dp =
      reinterpret_cast<const float4*>(data + ((size_t)b * NT + t) * NC);
#pragma unroll
  for (int i = 0; i < 4; ++i) {
    float4 v = dp[i];
    z0[4 * i + 0] = v.x - mu[4 * i + 0];
    z0[4 * i + 1] = v.y - mu[4 * i + 1];
    z0[4 * i + 2] = v.z - mu[4 * i + 2];
    z0[4 * i + 3] = v.w - mu[4 * i + 3];
  }
#pragma unroll
  for (int i = 0; i < 4; ++i) {
    float4 v = dp[4 + i];
    z1[4 * i + 0] = v.x - mu[16 + 4 * i + 0];
    z1[4 * i + 1] = v.y - mu[16 + 4 * i + 1];
    z1[4 * i + 2] = v.z - mu[16 + 4 * i + 2];
    z1[4 * i + 3] = v.w - mu[16 + 4 * i + 3];
  }
#pragma unroll
  for (int i = 0; i < 4; ++i) {
    float4 v = dp[8 + i];
    z2[4 * i + 0] = v.x - mu[32 + 4 * i + 0];
    z2[4 * i + 1] = v.y - mu[32 + 4 * i + 1];
    z2[4 * i + 2] = v.z - mu[32 + 4 * i + 2];
    z2[4 * i + 3] = v.w - mu[32 + 4 * i + 3];
  }
#pragma unroll
  for (int i = 0; i < 4; ++i) {
    float4 v = dp[12 + i];
    z3[4 * i + 0] = v.x - mu[48 + 4 * i + 0];
    z3[4 * i + 1] = v.y - mu[48 + 4 * i + 1];
    z3[4 * i + 2] = v.z - mu[48 + 4 * i + 2];
    z3[4 * i + 3] = v.w - mu[48 + 4 * i + 3];
  }

  // forward substitution, quad = ||z||^2 (fully static, register-resident)
  float quad = 0.0f;
  Row<0>::run(z0, z1, z2, z3, Lb, quad);

  // weighted log-prob contribution (constant term folded into finalize)
  float g = gamma[((size_t)b * NT + t) * NK + k];
  float w = g * (-0.5f * quad - ld);

#pragma unroll
  for (int off = 1; off < 64; off <<= 1) w += __shfl_xor(w, off);

  __shared__ float red[4];
  if (lane == 0) red[tid >> 6] = w;
  __syncthreads();
  if (tid == 0) solve_part[blockIdx.x] = red[0] + red[1] + red[2] + red[3];
}

// One block per (s,k); absent subjects write zero partials and exit.
__global__ __launch_bounds__(256) void reg_kernel(
    const float* __restrict__ mu_pop,   // (K,C)
    const float* __restrict__ L_pop,    // (K,C,C)
    const float* __restrict__ mu_subj,  // (S,K,C)
    const float* __restrict__ L_subj,   // (S,K,C,C)
    const int*   __restrict__ present,
    float*       __restrict__ mu_part,
    float*       __restrict__ L_part) {
  int bid = blockIdx.x;
  int s = bid / NK;
  int k = bid % NK;
  int tid = threadIdx.x;
  if (present[s] == 0) {
    if (tid == 0) {
      mu_part[bid] = 0.0f;
      L_part[bid] = 0.0f;
    }
    return;
  }

  const float4* Ls =
      reinterpret_cast<const float4*>(L_subj + (size_t)(s * NK + k) * (NC * NC));
  const float4* Lp =
      reinterpret_cast<const float4*>(L_pop + (size_t)k * (NC * NC));
  float sl = 0.0f;
#pragma unroll
  for (int i = 0; i < 4; ++i) {
    int idx = tid + i * 256;
    float4 a = Ls[idx], p = Lp[idx];
    float dx = a.x - p.x, dy = a.y - p.y, dz = a.z - p.z, dw = a.w - p.w;
    sl += dx * dx + dy * dy + dz * dz + dw * dw;
  }
  float sm = 0.0f;
  if (tid < NC) {
    float d = mu_subj[(size_t)(s * NK + k) * NC + tid] - mu_pop[k * NC + tid];
    sm = d * d;
  }
#pragma unroll
  for (int off = 1; off < 64; off <<= 1) {
    sl += __shfl_xor(sl, off);
    sm += __shfl_xor(sm, off);
  }
  __shared__ float rl[4], rm[4];
  int lane = tid & 63;
  if (lane == 0) {
    rl[tid >> 6] = sl;
    rm[tid >> 6] = sm;
  }
  __syncthreads();
  if (tid == 0) {
    mu_part[bid] = rm[0] + rm[1] + rm[2] + rm[3];
    L_part[bid] = rl[0] + rl[1] + rl[2] + rl[3];
  }
}

// Deterministic parallel reduce of all partials + final combine.
__global__ __launch_bounds__(256) void finalize_kernel(
    const float* __restrict__ solve_part, const float* __restrict__ mu_part,
    const float* __restrict__ L_part, const int* __restrict__ present,
    float* __restrict__ out) {
  int tid = threadIdx.x;
  double s_ll = 0.0, s_mu = 0.0, s_L = 0.0;
  for (int i = tid; i < SOLVE_BLOCKS; i += 256) s_ll += (double)solve_part[i];
  for (int i = tid; i < REG_BLOCKS; i += 256) {
    s_mu += (double)mu_part[i];
    s_L += (double)L_part[i];
  }
  int cnt = (tid < NS) ? present[tid] : 0;
#pragma unroll
  for (int off = 1; off < 64; off <<= 1) {
    s_ll += __shfl_xor(s_ll, off);
    s_mu += __shfl_xor(s_mu, off);
    s_L += __shfl_xor(s_L, off);
    cnt += __shfl_xor(cnt, off);
  }
  __shared__ double r0[4], r1[4], r2[4];
  __shared__ int r3[4];
  int lane = tid & 63;
  if (lane == 0) {
    r0[tid >> 6] = s_ll;
    r1[tid >> 6] = s_mu;
    r2[tid >> 6] = s_L;
    r3[tid >> 6] = cnt;
  }
  __syncthreads();
  if (tid == 0) {
    double ll_sum = r0[0] + r0[1] + r0[2] + r0[3];
    double mu_reg = r1[0] + r1[1] + r1[2] + r1[3];
    double L_reg = r2[0] + r2[1] + r2[2] + r2[3];
    int c = r3[0] + r3[1] + r3[2] + r3[3];
    double c0 = 0.5 * (double)NC * log(2.0 * M_PI);
    double ll = ll_sum / (double)NB - (double)NT * c0;
    double reg = (0.5 * mu_reg + 0.5 * L_reg) * ((double)c / (double)NS);
    out[0] = (float)(-ll + reg);
  }
}

extern "C" void kernel_launch(void* const* d_in, const int* in_sizes, int n_in,
                              void* d_out, int out_size, void* d_ws,
                              size_t ws_size, hipStream_t stream) {
  const float* data    = (const float*)d_in[0];
  const float* mu_pop  = (const float*)d_in[1];
  const float* L_pop   = (const float*)d_in[2];
  const float* mu_subj = (const float*)d_in[3];
  const float* L_subj  = (const float*)d_in[4];
  const float* gamma   = (const float*)d_in[5];
  const int*   sids    = (const int*)d_in[6];
  float* out = (float*)d_out;

  float* solve_part = (float*)d_ws;
  float* mu_part    = solve_part + SOLVE_BLOCKS;
  float* L_part     = mu_part + REG_BLOCKS;
  int*   present    = (int*)(L_part + REG_BLOCKS);

  hipLaunchKernelGGL(init_kernel, dim3(1), dim3(128), 0, stream, present);
  hipLaunchKernelGGL(solve_kernel, dim3(SOLVE_BLOCKS), dim3(256), 0, stream,
                     data, mu_subj, L_subj, gamma, sids, solve_part, present);
  hipLaunchKernelGGL(reg_kernel, dim3(REG_BLOCKS), dim3(256), 0, stream,
                     mu_pop, L_pop, mu_subj, L_subj, present, mu_part, L_part);
  hipLaunchKernelGGL(finalize_kernel, dim3(1), dim3(256), 0, stream,
                     solve_part, mu_part, L_part, present, out);
}

// Round 4
// 49.458 us; speedup vs baseline: 1.2036x; 1.0879x over previous
//
#include <hip/hip_runtime.h>
#include <math.h>

#define NB 32
#define NT 1024
#define NK 12
#define NC 64
#define NS 100
#define SOLVE_BLOCKS (NB * NK * 4)  // 1536
#define REG_BLOCKS (NS * NK)        // 1200

// ---------------------------------------------------------------------------
// ws layout (floats): solve_part[1536] | mu_part[1200] | L_part[1200] | int present[100]
// ---------------------------------------------------------------------------

__global__ __launch_bounds__(128) void init_kernel(int* __restrict__ present) {
  int tid = threadIdx.x;
  if (tid < NS) present[tid] = 0;
}

// Forward substitution with L read from LDS as wave-uniform broadcast
// ds_read_b128 (4 vals/inst, conflict-free). Template recursion keeps all
// z[] indices compile-time constant. Two accumulators halve the dependent
// FMA latency chain per row.
template <int C>
struct Row {
  static __device__ __forceinline__ void run(float (&z)[NC],
                                             const float4* __restrict__ Ls4,
                                             float& quad) {
    float a0 = z[C];
    float a1 = 0.0f;
    float diag = 0.0f;
#pragma unroll
    for (int g = 0; g <= C / 4; ++g) {
      float4 v = Ls4[C * 16 + g];
#pragma unroll
      for (int e = 0; e < 4; ++e) {
        int j = 4 * g + e;
        float ve = (e == 0) ? v.x : (e == 1) ? v.y : (e == 2) ? v.z : v.w;
        if (j < C) {
          if (j & 1)
            a1 = fmaf(-ve, z[j], a1);
          else
            a0 = fmaf(-ve, z[j], a0);
        } else if (j == C) {
          diag = ve;
        }
      }
    }
    float zc = (a0 + a1) * __builtin_amdgcn_rcpf(diag);
    z[C] = zc;
    quad = fmaf(zc, zc, quad);
    Row<C + 1>::run(z, Ls4, quad);
  }
};
template <>
struct Row<NC> {
  static __device__ __forceinline__ void run(float (&)[NC], const float4*,
                                             float&) {}
};

// One thread per (b,k,t). L staged in LDS once per block; per-block partial
// written to ws (no atomics).
__global__ __launch_bounds__(256) void solve_kernel(
    const float* __restrict__ data,      // (B,T,C)
    const float* __restrict__ mu_subj,   // (S,K,C)
    const float* __restrict__ L_subj,    // (S,K,C,C)
    const float* __restrict__ gamma,     // (B,T,K)
    const int*   __restrict__ sids,      // (B,1)
    float*       __restrict__ solve_part,
    int*         __restrict__ present) {
  // XCD-aware decode: all 48 (k,tile) blocks of one b land on one XCD ->
  // data/gamma L2 reuse across k.
  int blk  = blockIdx.x;
  int x    = blk & 7;
  int r    = blk >> 3;          // [0,192)
  int b    = (r / 48) * 8 + x;  // [0,32)
  int kt   = r % 48;
  int k    = kt >> 2;           // [0,12)
  int tile = kt & 3;            // [0,4)
  int tid  = threadIdx.x;
  int lane = tid & 63;
  int t    = tile * 256 + tid;

  int sid = __builtin_amdgcn_readfirstlane(sids[b]);
  if (tid == 0 && k == 0 && tile == 0) present[sid] = 1;

  const float* __restrict__ Lb = L_subj + (size_t)(sid * NK + k) * (NC * NC);
  const float* __restrict__ mu = mu_subj + (size_t)(sid * NK + k) * NC;

  // Stage L (16 KB) into LDS, coalesced float4.
  __shared__ float4 Ls4[NC * NC / 4];
  const float4* Lg = reinterpret_cast<const float4*>(Lb);
#pragma unroll
  for (int i = 0; i < 4; ++i) Ls4[tid + 256 * i] = Lg[tid + 256 * i];
  __syncthreads();

  // logdet = sum log diag(L) from LDS: lane-parallel + wave reduce
  const float* Lsf = reinterpret_cast<const float*>(Ls4);
  float ld = __logf(Lsf[lane * (NC + 1)]);
#pragma unroll
  for (int off = 1; off < 64; off <<= 1) ld += __shfl_xor(ld, off);

  // diff -> z[]
  float z[NC];
  const float4* dp =
      reinterpret_cast<const float4*>(data + ((size_t)b * NT + t) * NC);
#pragma unroll
  for (int i = 0; i < NC / 4; ++i) {
    float4 v = dp[i];
    z[4 * i + 0] = v.x - mu[4 * i + 0];
    z[4 * i + 1] = v.y - mu[4 * i + 1];
    z[4 * i + 2] = v.z - mu[4 * i + 2];
    z[4 * i + 3] = v.w - mu[4 * i + 3];
  }

  // forward substitution, quad = ||z||^2 (L from LDS)
  float quad = 0.0f;
  Row<0>::run(z, Ls4, quad);

  // weighted log-prob contribution (constant term folded into finalize)
  float g = gamma[((size_t)b * NT + t) * NK + k];
  float w = g * (-0.5f * quad - ld);

#pragma unroll
  for (int off = 1; off < 64; off <<= 1) w += __shfl_xor(w, off);

  __shared__ float red[4];
  if (lane == 0) red[tid >> 6] = w;
  __syncthreads();
  if (tid == 0) solve_part[blockIdx.x] = red[0] + red[1] + red[2] + red[3];
}

// One block per (s,k); absent subjects write zero partials and exit.
__global__ __launch_bounds__(256) void reg_kernel(
    const float* __restrict__ mu_pop,   // (K,C)
    const float* __restrict__ L_pop,    // (K,C,C)
    const float* __restrict__ mu_subj,  // (S,K,C)
    const float* __restrict__ L_subj,   // (S,K,C,C)
    const int*   __restrict__ present,
    float*       __restrict__ mu_part,
    float*       __restrict__ L_part) {
  int bid = blockIdx.x;
  int s = bid / NK;
  int k = bid % NK;
  int tid = threadIdx.x;
  if (present[s] == 0) {
    if (tid == 0) {
      mu_part[bid] = 0.0f;
      L_part[bid] = 0.0f;
    }
    return;
  }

  const float4* Ls =
      reinterpret_cast<const float4*>(L_subj + (size_t)(s * NK + k) * (NC * NC));
  const float4* Lp =
      reinterpret_cast<const float4*>(L_pop + (size_t)k * (NC * NC));
  float sl = 0.0f;
#pragma unroll
  for (int i = 0; i < 4; ++i) {
    int idx = tid + i * 256;
    float4 a = Ls[idx], p = Lp[idx];
    float dx = a.x - p.x, dy = a.y - p.y, dz = a.z - p.z, dw = a.w - p.w;
    sl += dx * dx + dy * dy + dz * dz + dw * dw;
  }
  float sm = 0.0f;
  if (tid < NC) {
    float d = mu_subj[(size_t)(s * NK + k) * NC + tid] - mu_pop[k * NC + tid];
    sm = d * d;
  }
#pragma unroll
  for (int off = 1; off < 64; off <<= 1) {
    sl += __shfl_xor(sl, off);
    sm += __shfl_xor(sm, off);
  }
  __shared__ float rl[4], rm[4];
  int lane = tid & 63;
  if (lane == 0) {
    rl[tid >> 6] = sl;
    rm[tid >> 6] = sm;
  }
  __syncthreads();
  if (tid == 0) {
    mu_part[bid] = rm[0] + rm[1] + rm[2] + rm[3];
    L_part[bid] = rl[0] + rl[1] + rl[2] + rl[3];
  }
}

// Deterministic parallel reduce of all partials + final combine.
__global__ __launch_bounds__(256) void finalize_kernel(
    const float* __restrict__ solve_part, const float* __restrict__ mu_part,
    const float* __restrict__ L_part, const int* __restrict__ present,
    float* __restrict__ out) {
  int tid = threadIdx.x;
  double s_ll = 0.0, s_mu = 0.0, s_L = 0.0;
  for (int i = tid; i < SOLVE_BLOCKS; i += 256) s_ll += (double)solve_part[i];
  for (int i = tid; i < REG_BLOCKS; i += 256) {
    s_mu += (double)mu_part[i];
    s_L += (double)L_part[i];
  }
  int cnt = (tid < NS) ? present[tid] : 0;
#pragma unroll
  for (int off = 1; off < 64; off <<= 1) {
    s_ll += __shfl_xor(s_ll, off);
    s_mu += __shfl_xor(s_mu, off);
    s_L += __shfl_xor(s_L, off);
    cnt += __shfl_xor(cnt, off);
  }
  __shared__ double r0[4], r1[4], r2[4];
  __shared__ int r3[4];
  int lane = tid & 63;
  if (lane == 0) {
    r0[tid >> 6] = s_ll;
    r1[tid >> 6] = s_mu;
    r2[tid >> 6] = s_L;
    r3[tid >> 6] = cnt;
  }
  __syncthreads();
  if (tid == 0) {
    double ll_sum = r0[0] + r0[1] + r0[2] + r0[3];
    double mu_reg = r1[0] + r1[1] + r1[2] + r1[3];
    double L_reg = r2[0] + r2[1] + r2[2] + r2[3];
    int c = r3[0] + r3[1] + r3[2] + r3[3];
    double c0 = 0.5 * (double)NC * log(2.0 * M_PI);
    double ll = ll_sum / (double)NB - (double)NT * c0;
    double reg = (0.5 * mu_reg + 0.5 * L_reg) * ((double)c / (double)NS);
    out[0] = (float)(-ll + reg);
  }
}

extern "C" void kernel_launch(void* const* d_in, const int* in_sizes, int n_in,
                              void* d_out, int out_size, void* d_ws,
                              size_t ws_size, hipStream_t stream) {
  const float* data    = (const float*)d_in[0];
  const float* mu_pop  = (const float*)d_in[1];
  const float* L_pop   = (const float*)d_in[2];
  const float* mu_subj = (const float*)d_in[3];
  const float* L_subj  = (const float*)d_in[4];
  const float* gamma   = (const float*)d_in[5];
  const int*   sids    = (const int*)d_in[6];
  float* out = (float*)d_out;

  float* solve_part = (float*)d_ws;
  float* mu_part    = solve_part + SOLVE_BLOCKS;
  float* L_part     = mu_part + REG_BLOCKS;
  int*   present    = (int*)(L_part + REG_BLOCKS);

  hipLaunchKernelGGL(init_kernel, dim3(1), dim3(128), 0, stream, present);
  hipLaunchKernelGGL(solve_kernel, dim3(SOLVE_BLOCKS), dim3(256), 0, stream,
                     data, mu_subj, L_subj, gamma, sids, solve_part, present);
  hipLaunchKernelGGL(reg_kernel, dim3(REG_BLOCKS), dim3(256), 0, stream,
                     mu_pop, L_pop, mu_subj, L_subj, present, mu_part, L_part);
  hipLaunchKernelGGL(finalize_kernel, dim3(1), dim3(256), 0, stream,
                     solve_part, mu_part, L_part, present, out);
}

// Round 5
// 44.914 us; speedup vs baseline: 1.3254x; 1.1012x over previous
//
#include <hip/hip_runtime.h>
#include <math.h>

#define NB 32
#define NT 1024
#define NK 12
#define NC 64
#define NS 100
#define SOLVE_BLOCKS (NB * NK * 4)  // 1536 (mfma blocks: b,k,quarter)
#define REG_BLOCKS (NS * NK)        // 1200

typedef __attribute__((ext_vector_type(8))) short short8v;  // 8 bf16 (A/B frag)
typedef __attribute__((ext_vector_type(4))) float f32x4;    // C/D frag

// ---------------------------------------------------------------------------
// ws layout: bf16 W[384*4096] (3 MB) | float solve_part[1536] | mu_part[1200]
//            | L_part[1200] | int present[100]
// ---------------------------------------------------------------------------

__device__ __forceinline__ short f2bf(float f) {
  union { float f; unsigned u; } v{f};
  unsigned r = v.u + 0x7fffu + ((v.u >> 16) & 1u);  // RNE (finite inputs)
  return (short)(r >> 16);
}

__global__ __launch_bounds__(128) void init_kernel(int* __restrict__ present) {
  int tid = threadIdx.x;
  if (tid < NS) present[tid] = 0;
}

// Static forward substitution (L from LDS via broadcast ds_read_b128).
template <int C>
struct Row {
  static __device__ __forceinline__ void run(float (&z)[NC],
                                             const float4* __restrict__ Ls4,
                                             float& quad) {
    float a0 = z[C];
    float a1 = 0.0f;
    float diag = 0.0f;
#pragma unroll
    for (int g = 0; g <= C / 4; ++g) {
      float4 v = Ls4[C * 16 + g];
#pragma unroll
      for (int e = 0; e < 4; ++e) {
        int j = 4 * g + e;
        float ve = (e == 0) ? v.x : (e == 1) ? v.y : (e == 2) ? v.z : v.w;
        if (j < C) {
          if (j & 1)
            a1 = fmaf(-ve, z[j], a1);
          else
            a0 = fmaf(-ve, z[j], a0);
        } else if (j == C) {
          diag = ve;
        }
      }
    }
    float zc = (a0 + a1) * __builtin_amdgcn_rcpf(diag);
    z[C] = zc;
    quad = fmaf(zc, zc, quad);
    Row<C + 1>::run(z, Ls4, quad);
  }
};
template <>
struct Row<NC> {
  static __device__ __forceinline__ void run(float (&)[NC], const float4*,
                                             float&) {}
};

// One wave per (b,k): W = L^{-1}, lane j solves column e_j; transpose via
// padded LDS; coalesced bf16 row-major store to ws.
__global__ __launch_bounds__(64) void invert_kernel(
    const float* __restrict__ L_subj, const int* __restrict__ sids,
    unsigned short* __restrict__ Wws) {
  int b = blockIdx.x / NK;
  int k = blockIdx.x % NK;
  int j = threadIdx.x;
  int sid = __builtin_amdgcn_readfirstlane(sids[b]);

  __shared__ float4 Ls4[NC * NC / 4];
  const float4* Lg =
      reinterpret_cast<const float4*>(L_subj + (size_t)(sid * NK + k) * NC * NC);
#pragma unroll
  for (int i = 0; i < 16; ++i) Ls4[j + 64 * i] = Lg[j + 64 * i];
  __syncthreads();

  float z[NC];
#pragma unroll
  for (int c = 0; c < NC; ++c) z[c] = (c == j) ? 1.0f : 0.0f;
  float dummy = 0.0f;
  Row<0>::run(z, Ls4, dummy);

  // transpose: lane j holds column j -> Wlds[row][j] (padded, conflict-free)
  __shared__ float Wlds[NC * (NC + 1)];
#pragma unroll
  for (int r = 0; r < NC; ++r) Wlds[r * (NC + 1) + j] = z[r];
  __syncthreads();

  // lane j writes row j as 32 packed u32 (coalesced-ish per-lane chunks)
  const float* wr = Wlds + j * (NC + 1);
  unsigned* dst =
      reinterpret_cast<unsigned*>(Wws + (size_t)(b * NK + k) * NC * NC) + j * 32;
#pragma unroll
  for (int i = 0; i < 32; ++i) {
    unsigned lo = (unsigned short)f2bf(wr[2 * i]);
    unsigned hi = (unsigned short)f2bf(wr[2 * i + 1]);
    dst[i] = lo | (hi << 16);
  }
}

// One wave per (b,k,quarter): Z = W * (x - mu) via mfma_f32_16x16x32_bf16,
// fused quad extraction + gamma weighting + wave reduce.
__global__ __launch_bounds__(64) void mfma_kernel(
    const float* __restrict__ data,      // (B,T,C)
    const float* __restrict__ mu_subj,   // (S,K,C)
    const float* __restrict__ L_subj,    // (S,K,C,C)
    const float* __restrict__ gamma,     // (B,T,K)
    const int*   __restrict__ sids,      // (B,1)
    const unsigned short* __restrict__ Wws,
    float* __restrict__ solve_part,
    int*   __restrict__ present) {
  // XCD-aware decode: all 48 (k,q) blocks of one b on one XCD (data L2 reuse).
  int blk = blockIdx.x;
  int x   = blk & 7;
  int r   = blk >> 3;          // [0,192)
  int b   = (r / 48) * 8 + x;  // [0,32)
  int rem = r % 48;
  int k   = rem >> 2;          // [0,12)
  int q   = rem & 3;           // quarter: 256 t each
  int lane = threadIdx.x;
  int g = lane >> 4;           // k-group 0..3
  int m = lane & 15;           // row (A) / col (B,C)

  int sid = __builtin_amdgcn_readfirstlane(sids[b]);
  if (lane == 0 && k == 0 && q == 0) present[sid] = 1;

  // logdet from L diag
  const float* Lb = L_subj + (size_t)(sid * NK + k) * NC * NC;
  float ld = __logf(Lb[lane * (NC + 1)]);
#pragma unroll
  for (int off = 1; off < 64; off <<= 1) ld += __shfl_xor(ld, off);

  // A-frags: W rows. afrag[ct][kk] = W[ct*16+m][kk*32+g*8 .. +7] (contiguous)
  const unsigned short* Wp = Wws + (size_t)(b * NK + k) * NC * NC;
  short8v afrag[4][2];
#pragma unroll
  for (int ct = 0; ct < 4; ++ct)
#pragma unroll
    for (int kk = 0; kk < 2; ++kk)
      afrag[ct][kk] = *reinterpret_cast<const short8v*>(
          Wp + (ct * 16 + m) * NC + kk * 32 + g * 8);

  // mu slice for this lane's k-positions
  const float* mu = mu_subj + (size_t)(sid * NK + k) * NC;
  float4 mu0a = *reinterpret_cast<const float4*>(mu + g * 8);
  float4 mu0b = *reinterpret_cast<const float4*>(mu + g * 8 + 4);
  float4 mu1a = *reinterpret_cast<const float4*>(mu + 32 + g * 8);
  float4 mu1b = *reinterpret_cast<const float4*>(mu + 32 + g * 8 + 4);

  float wacc = 0.0f;
  int t0 = q * 256;
#pragma unroll 2
  for (int tt = 0; tt < 16; ++tt) {
    int t = t0 + tt * 16 + m;
    const float* dp = data + ((size_t)(b * NT + t)) * NC;

    // B-frags: d[c] slices (contiguous in memory)
    short8v bf0, bf1;
    {
      const float4* dv = reinterpret_cast<const float4*>(dp + g * 8);
      float4 v0 = dv[0], v1 = dv[1];
      bf0[0] = f2bf(v0.x - mu0a.x);
      bf0[1] = f2bf(v0.y - mu0a.y);
      bf0[2] = f2bf(v0.z - mu0a.z);
      bf0[3] = f2bf(v0.w - mu0a.w);
      bf0[4] = f2bf(v1.x - mu0b.x);
      bf0[5] = f2bf(v1.y - mu0b.y);
      bf0[6] = f2bf(v1.z - mu0b.z);
      bf0[7] = f2bf(v1.w - mu0b.w);
    }
    {
      const float4* dv = reinterpret_cast<const float4*>(dp + 32 + g * 8);
      float4 v0 = dv[0], v1 = dv[1];
      bf1[0] = f2bf(v0.x - mu1a.x);
      bf1[1] = f2bf(v0.y - mu1a.y);
      bf1[2] = f2bf(v0.z - mu1a.z);
      bf1[3] = f2bf(v0.w - mu1a.w);
      bf1[4] = f2bf(v1.x - mu1b.x);
      bf1[5] = f2bf(v1.y - mu1b.y);
      bf1[6] = f2bf(v1.z - mu1b.z);
      bf1[7] = f2bf(v1.w - mu1b.w);
    }

    f32x4 acc0 = {0.f, 0.f, 0.f, 0.f}, acc1 = acc0, acc2 = acc0, acc3 = acc0;
    acc0 = __builtin_amdgcn_mfma_f32_16x16x32_bf16(afrag[0][0], bf0, acc0, 0, 0, 0);
    acc0 = __builtin_amdgcn_mfma_f32_16x16x32_bf16(afrag[0][1], bf1, acc0, 0, 0, 0);
    acc1 = __builtin_amdgcn_mfma_f32_16x16x32_bf16(afrag[1][0], bf0, acc1, 0, 0, 0);
    acc1 = __builtin_amdgcn_mfma_f32_16x16x32_bf16(afrag[1][1], bf1, acc1, 0, 0, 0);
    acc2 = __builtin_amdgcn_mfma_f32_16x16x32_bf16(afrag[2][0], bf0, acc2, 0, 0, 0);
    acc2 = __builtin_amdgcn_mfma_f32_16x16x32_bf16(afrag[2][1], bf1, acc2, 0, 0, 0);
    acc3 = __builtin_amdgcn_mfma_f32_16x16x32_bf16(afrag[3][0], bf0, acc3, 0, 0, 0);
    acc3 = __builtin_amdgcn_mfma_f32_16x16x32_bf16(afrag[3][1], bf1, acc3, 0, 0, 0);

    // quad for col t: sum z^2 over the 16 rows this lane holds, then fold
    // the 4 lane-groups (xor16 + xor32).
    float s = 0.0f;
#pragma unroll
    for (int e = 0; e < 4; ++e) {
      s = fmaf(acc0[e], acc0[e], s);
      s = fmaf(acc1[e], acc1[e], s);
      s = fmaf(acc2[e], acc2[e], s);
      s = fmaf(acc3[e], acc3[e], s);
    }
    s += __shfl_xor(s, 16);
    s += __shfl_xor(s, 32);

    float gam = gamma[((size_t)(b * NT + t)) * NK + k];
    wacc = fmaf(gam, -0.5f * s - ld, wacc);
  }

  // full 64-lane reduce; each t counted 4x (lane-group duplication) -> *0.25
#pragma unroll
  for (int off = 1; off < 64; off <<= 1) wacc += __shfl_xor(wacc, off);
  if (lane == 0) solve_part[blockIdx.x] = wacc * 0.25f;
}

// One block per (s,k); absent subjects write zero partials and exit.
__global__ __launch_bounds__(256) void reg_kernel(
    const float* __restrict__ mu_pop, const float* __restrict__ L_pop,
    const float* __restrict__ mu_subj, const float* __restrict__ L_subj,
    const int* __restrict__ present, float* __restrict__ mu_part,
    float* __restrict__ L_part) {
  int bid = blockIdx.x;
  int s = bid / NK;
  int k = bid % NK;
  int tid = threadIdx.x;
  if (present[s] == 0) {
    if (tid == 0) {
      mu_part[bid] = 0.0f;
      L_part[bid] = 0.0f;
    }
    return;
  }

  const float4* Ls =
      reinterpret_cast<const float4*>(L_subj + (size_t)(s * NK + k) * NC * NC);
  const float4* Lp =
      reinterpret_cast<const float4*>(L_pop + (size_t)k * NC * NC);
  float sl = 0.0f;
#pragma unroll
  for (int i = 0; i < 4; ++i) {
    int idx = tid + i * 256;
    float4 a = Ls[idx], p = Lp[idx];
    float dx = a.x - p.x, dy = a.y - p.y, dz = a.z - p.z, dw = a.w - p.w;
    sl += dx * dx + dy * dy + dz * dz + dw * dw;
  }
  float sm = 0.0f;
  if (tid < NC) {
    float d = mu_subj[(size_t)(s * NK + k) * NC + tid] - mu_pop[k * NC + tid];
    sm = d * d;
  }
#pragma unroll
  for (int off = 1; off < 64; off <<= 1) {
    sl += __shfl_xor(sl, off);
    sm += __shfl_xor(sm, off);
  }
  __shared__ float rl[4], rm[4];
  int lane = tid & 63;
  if (lane == 0) {
    rl[tid >> 6] = sl;
    rm[tid >> 6] = sm;
  }
  __syncthreads();
  if (tid == 0) {
    mu_part[bid] = rm[0] + rm[1] + rm[2] + rm[3];
    L_part[bid] = rl[0] + rl[1] + rl[2] + rl[3];
  }
}

// Deterministic parallel reduce of all partials + final combine.
__global__ __launch_bounds__(256) void finalize_kernel(
    const float* __restrict__ solve_part, const float* __restrict__ mu_part,
    const float* __restrict__ L_part, const int* __restrict__ present,
    float* __restrict__ out) {
  int tid = threadIdx.x;
  double s_ll = 0.0, s_mu = 0.0, s_L = 0.0;
  for (int i = tid; i < SOLVE_BLOCKS; i += 256) s_ll += (double)solve_part[i];
  for (int i = tid; i < REG_BLOCKS; i += 256) {
    s_mu += (double)mu_part[i];
    s_L += (double)L_part[i];
  }
  int cnt = (tid < NS) ? present[tid] : 0;
#pragma unroll
  for (int off = 1; off < 64; off <<= 1) {
    s_ll += __shfl_xor(s_ll, off);
    s_mu += __shfl_xor(s_mu, off);
    s_L += __shfl_xor(s_L, off);
    cnt += __shfl_xor(cnt, off);
  }
  __shared__ double r0[4], r1[4], r2[4];
  __shared__ int r3[4];
  int lane = tid & 63;
  if (lane == 0) {
    r0[tid >> 6] = s_ll;
    r1[tid >> 6] = s_mu;
    r2[tid >> 6] = s_L;
    r3[tid >> 6] = cnt;
  }
  __syncthreads();
  if (tid == 0) {
    double ll_sum = r0[0] + r0[1] + r0[2] + r0[3];
    double mu_reg = r1[0] + r1[1] + r1[2] + r1[3];
    double L_reg = r2[0] + r2[1] + r2[2] + r2[3];
    int c = r3[0] + r3[1] + r3[2] + r3[3];
    double c0 = 0.5 * (double)NC * log(2.0 * M_PI);
    double ll = ll_sum / (double)NB - (double)NT * c0;
    double reg = (0.5 * mu_reg + 0.5 * L_reg) * ((double)c / (double)NS);
    out[0] = (float)(-ll + reg);
  }
}

extern "C" void kernel_launch(void* const* d_in, const int* in_sizes, int n_in,
                              void* d_out, int out_size, void* d_ws,
                              size_t ws_size, hipStream_t stream) {
  const float* data    = (const float*)d_in[0];
  const float* mu_pop  = (const float*)d_in[1];
  const float* L_pop   = (const float*)d_in[2];
  const float* mu_subj = (const float*)d_in[3];
  const float* L_subj  = (const float*)d_in[4];
  const float* gamma   = (const float*)d_in[5];
  const int*   sids    = (const int*)d_in[6];
  float* out = (float*)d_out;

  unsigned short* Wws = (unsigned short*)d_ws;  // 384*4096 bf16 = 3 MB
  float* solve_part = (float*)((char*)d_ws + (size_t)NB * NK * NC * NC * 2);
  float* mu_part    = solve_part + SOLVE_BLOCKS;
  float* L_part     = mu_part + REG_BLOCKS;
  int*   present    = (int*)(L_part + REG_BLOCKS);

  hipLaunchKernelGGL(init_kernel, dim3(1), dim3(128), 0, stream, present);
  hipLaunchKernelGGL(invert_kernel, dim3(NB * NK), dim3(64), 0, stream,
                     L_subj, sids, Wws);
  hipLaunchKernelGGL(mfma_kernel, dim3(SOLVE_BLOCKS), dim3(64), 0, stream,
                     data, mu_subj, L_subj, gamma, sids, Wws, solve_part,
                     present);
  hipLaunchKernelGGL(reg_kernel, dim3(REG_BLOCKS), dim3(256), 0, stream,
                     mu_pop, L_pop, mu_subj, L_subj, present, mu_part, L_part);
  hipLaunchKernelGGL(finalize_kernel, dim3(1), dim3(256), 0, stream,
                     solve_part, mu_part, L_part, present, out);
}

// Round 6
// 43.242 us; speedup vs baseline: 1.3766x; 1.0387x over previous
//
#include <hip/hip_runtime.h>
#include <hip/hip_bf16.h>
#include <math.h>

#define NB 32
#define NT 1024
#define NK 12
#define NC 64
#define NS 100
#define INV_BLOCKS (NB * NK)        // 384
#define REG_BLOCKS (NS * NK)        // 1200
#define PREP_BLOCKS (INV_BLOCKS + REG_BLOCKS)
#define MFMA_BLOCKS (NB * NK * 8)   // 3072

typedef __attribute__((ext_vector_type(8))) short short8v;  // 8 bf16
typedef __attribute__((ext_vector_type(4))) float f32x4;

// ---------------------------------------------------------------------------
// ws: bf16 W[384*4096] (3MB) | float ldws[384] | solve_part[3072]
//     | mu_part[1200] | L_part[1200]
// ---------------------------------------------------------------------------

__device__ __forceinline__ unsigned pk2(float a, float b) {
  float2 f2{a, b};
  __hip_bfloat162 h = __float22bfloat162_rn(f2);
  union { __hip_bfloat162 h; unsigned u; } c{h};
  return c.u;
}

// Static forward substitution (L from LDS via broadcast ds_read_b128).
template <int C>
struct Row {
  static __device__ __forceinline__ void run(float (&z)[NC],
                                             const float4* __restrict__ Ls4,
                                             float& quad) {
    float a0 = z[C];
    float a1 = 0.0f;
    float diag = 0.0f;
#pragma unroll
    for (int g = 0; g <= C / 4; ++g) {
      float4 v = Ls4[C * 16 + g];
#pragma unroll
      for (int e = 0; e < 4; ++e) {
        int j = 4 * g + e;
        float ve = (e == 0) ? v.x : (e == 1) ? v.y : (e == 2) ? v.z : v.w;
        if (j < C) {
          if (j & 1)
            a1 = fmaf(-ve, z[j], a1);
          else
            a0 = fmaf(-ve, z[j], a0);
        } else if (j == C) {
          diag = ve;
        }
      }
    }
    float zc = (a0 + a1) * __builtin_amdgcn_rcpf(diag);
    z[C] = zc;
    quad = fmaf(zc, zc, quad);
    Row<C + 1>::run(z, Ls4, quad);
  }
};
template <>
struct Row<NC> {
  static __device__ __forceinline__ void run(float (&)[NC], const float4*,
                                             float&) {}
};

// Blocks [0,384): invert W=L^{-1} (bf16) + logdet.  Blocks [384,1584): reg.
__global__ __launch_bounds__(256) void prep_kernel(
    const float* __restrict__ mu_pop, const float* __restrict__ L_pop,
    const float* __restrict__ mu_subj, const float* __restrict__ L_subj,
    const int* __restrict__ sids, unsigned short* __restrict__ Wws,
    float* __restrict__ ldws, float* __restrict__ mu_part,
    float* __restrict__ L_part) {
  __shared__ float smem[NC * (NC + 1)];  // 16.6 KB: L (4096f) then W^T padded
  int bid = blockIdx.x;
  int tid = threadIdx.x;

  if (bid < INV_BLOCKS) {
    int b = bid / NK, k = bid % NK;
    int sid = __builtin_amdgcn_readfirstlane(sids[b]);
    // stage L with all 256 threads
    const float4* Lg =
        reinterpret_cast<const float4*>(L_subj + (size_t)(sid * NK + k) * NC * NC);
    float4* Ls4 = reinterpret_cast<float4*>(smem);
#pragma unroll
    for (int i = 0; i < 4; ++i) Ls4[tid + 256 * i] = Lg[tid + 256 * i];
    __syncthreads();

    int j = tid & 63;
    int wv = tid >> 6;
    float z[NC];
    float ld = 0.0f;
    if (wv == 0) {
      ld = __logf(smem[j * (NC + 1)]);  // diag: j*64+j
#pragma unroll
      for (int off = 1; off < 64; off <<= 1) ld += __shfl_xor(ld, off);
#pragma unroll
      for (int c = 0; c < NC; ++c) z[c] = (c == j) ? 1.0f : 0.0f;
      float dummy = 0.0f;
      Row<0>::run(z, reinterpret_cast<const float4*>(smem), dummy);
    }
    __syncthreads();  // substitution done; L no longer needed
    if (wv == 0) {
      // transpose: lane j holds column j -> smem[row][j] (65-padded)
#pragma unroll
      for (int rr = 0; rr < NC; ++rr) smem[rr * (NC + 1) + j] = z[rr];
      if (j == 0) ldws[bid] = ld;
    }
    __syncthreads();
    // all 256 threads store W row-major bf16, coalesced (2048 dwords)
    unsigned* dst = reinterpret_cast<unsigned*>(Wws + (size_t)bid * NC * NC);
#pragma unroll
    for (int i = 0; i < 8; ++i) {
      int flat = i * 256 + tid;  // [0,2048)
      int rr = flat >> 5;
      int c2 = flat & 31;
      dst[flat] = pk2(smem[rr * (NC + 1) + 2 * c2], smem[rr * (NC + 1) + 2 * c2 + 1]);
    }
    return;
  }

  // ---- reg part ----
  int rb = bid - INV_BLOCKS;
  int s = rb / NK, k = rb % NK;
  int lane = tid & 63;
  // presence: per-wave ballot over the 32 sids (no cross-block dependency)
  int sv = sids[lane & 31];
  bool pres = __ballot(sv == s) != 0ull;
  if (!pres) {
    if (tid == 0) {
      mu_part[rb] = 0.0f;
      L_part[rb] = 0.0f;
    }
    return;
  }

  const float4* Ls =
      reinterpret_cast<const float4*>(L_subj + (size_t)(s * NK + k) * NC * NC);
  const float4* Lp = reinterpret_cast<const float4*>(L_pop + (size_t)k * NC * NC);
  float sl = 0.0f;
#pragma unroll
  for (int i = 0; i < 4; ++i) {
    int idx = tid + i * 256;
    float4 a = Ls[idx], p = Lp[idx];
    float dx = a.x - p.x, dy = a.y - p.y, dz = a.z - p.z, dw = a.w - p.w;
    sl += dx * dx + dy * dy + dz * dz + dw * dw;
  }
  float sm = 0.0f;
  if (tid < NC) {
    float d = mu_subj[(size_t)(s * NK + k) * NC + tid] - mu_pop[k * NC + tid];
    sm = d * d;
  }
#pragma unroll
  for (int off = 1; off < 64; off <<= 1) {
    sl += __shfl_xor(sl, off);
    sm += __shfl_xor(sm, off);
  }
  if (lane == 0) {
    smem[tid >> 6] = sl;
    smem[4 + (tid >> 6)] = sm;
  }
  __syncthreads();
  if (tid == 0) {
    mu_part[rb] = smem[4] + smem[5] + smem[6] + smem[7];
    L_part[rb] = smem[0] + smem[1] + smem[2] + smem[3];
  }
}

// One wave per (b,k,octile of t). Z = W (x - mu) via mfma_f32_16x16x32_bf16.
__global__ __launch_bounds__(64) void mfma_kernel(
    const float* __restrict__ data,      // (B,T,C)
    const float* __restrict__ mu_subj,   // (S,K,C)
    const float* __restrict__ gamma,     // (B,T,K)
    const int*   __restrict__ sids,      // (B,1)
    const unsigned short* __restrict__ Wws,
    const float* __restrict__ ldws,
    float* __restrict__ solve_part) {
  // XCD-aware decode: 96 (k,q) blocks of 4 b's per XCD -> data/gamma/W L2-fit
  int blk = blockIdx.x;
  int x   = blk & 7;
  int r   = blk >> 3;          // [0,384)
  int b   = (r / 96) * 8 + x;  // [0,32)
  int rem = r % 96;
  int k   = rem >> 3;          // [0,12)
  int q   = rem & 7;           // octile: 128 t each
  int lane = threadIdx.x;
  int g = lane >> 4;           // k-group 0..3
  int m = lane & 15;           // row (A) / col (B,C)

  int sid = __builtin_amdgcn_readfirstlane(sids[b]);
  float ld4 = 0.25f * ldws[b * NK + k];  // each t's ld counted by 4 lanes

  int t0 = q * 128;
  // gamma preload: 8 independent loads, latency hidden
  float gpre[8];
#pragma unroll
  for (int tt = 0; tt < 8; ++tt)
    gpre[tt] = gamma[((size_t)(b * NT + t0 + tt * 16 + m)) * NK + k];

  // A-frags: W rows (bf16, row-major, contiguous per-lane 16B)
  const unsigned short* Wp = Wws + (size_t)(b * NK + k) * NC * NC;
  short8v afrag[4][2];
#pragma unroll
  for (int ct = 0; ct < 4; ++ct)
#pragma unroll
    for (int kk = 0; kk < 2; ++kk)
      afrag[ct][kk] = *reinterpret_cast<const short8v*>(
          Wp + (ct * 16 + m) * NC + kk * 32 + g * 8);

  const float* mu = mu_subj + (size_t)(sid * NK + k) * NC;
  float4 mu0a = *reinterpret_cast<const float4*>(mu + g * 8);
  float4 mu0b = *reinterpret_cast<const float4*>(mu + g * 8 + 4);
  float4 mu1a = *reinterpret_cast<const float4*>(mu + 32 + g * 8);
  float4 mu1b = *reinterpret_cast<const float4*>(mu + 32 + g * 8 + 4);

  float wacc = 0.0f;
#pragma unroll
  for (int tt = 0; tt < 8; ++tt) {
    int t = t0 + tt * 16 + m;
    const float* dp = data + ((size_t)(b * NT + t)) * NC;

    union { unsigned u[4]; short8v v; } ub0, ub1;
    {
      const float4* dv = reinterpret_cast<const float4*>(dp + g * 8);
      float4 v0 = dv[0], v1 = dv[1];
      ub0.u[0] = pk2(v0.x - mu0a.x, v0.y - mu0a.y);
      ub0.u[1] = pk2(v0.z - mu0a.z, v0.w - mu0a.w);
      ub0.u[2] = pk2(v1.x - mu0b.x, v1.y - mu0b.y);
      ub0.u[3] = pk2(v1.z - mu0b.z, v1.w - mu0b.w);
    }
    {
      const float4* dv = reinterpret_cast<const float4*>(dp + 32 + g * 8);
      float4 v0 = dv[0], v1 = dv[1];
      ub1.u[0] = pk2(v0.x - mu1a.x, v0.y - mu1a.y);
      ub1.u[1] = pk2(v0.z - mu1a.z, v0.w - mu1a.w);
      ub1.u[2] = pk2(v1.x - mu1b.x, v1.y - mu1b.y);
      ub1.u[3] = pk2(v1.z - mu1b.z, v1.w - mu1b.w);
    }

    f32x4 acc0 = {0.f, 0.f, 0.f, 0.f}, acc1 = acc0, acc2 = acc0, acc3 = acc0;
    acc0 = __builtin_amdgcn_mfma_f32_16x16x32_bf16(afrag[0][0], ub0.v, acc0, 0, 0, 0);
    acc0 = __builtin_amdgcn_mfma_f32_16x16x32_bf16(afrag[0][1], ub1.v, acc0, 0, 0, 0);
    acc1 = __builtin_amdgcn_mfma_f32_16x16x32_bf16(afrag[1][0], ub0.v, acc1, 0, 0, 0);
    acc1 = __builtin_amdgcn_mfma_f32_16x16x32_bf16(afrag[1][1], ub1.v, acc1, 0, 0, 0);
    acc2 = __builtin_amdgcn_mfma_f32_16x16x32_bf16(afrag[2][0], ub0.v, acc2, 0, 0, 0);
    acc2 = __builtin_amdgcn_mfma_f32_16x16x32_bf16(afrag[2][1], ub1.v, acc2, 0, 0, 0);
    acc3 = __builtin_amdgcn_mfma_f32_16x16x32_bf16(afrag[3][0], ub0.v, acc3, 0, 0, 0);
    acc3 = __builtin_amdgcn_mfma_f32_16x16x32_bf16(afrag[3][1], ub1.v, acc3, 0, 0, 0);

    // per-lane partial: 16 of the 64 rows of col t. gamma & ld folded
    // linearly (4 lanes per t share gamma; ld4 pre-scaled by 1/4).
    float s = 0.0f;
#pragma unroll
    for (int e = 0; e < 4; ++e) {
      s = fmaf(acc0[e], acc0[e], s);
      s = fmaf(acc1[e], acc1[e], s);
      s = fmaf(acc2[e], acc2[e], s);
      s = fmaf(acc3[e], acc3[e], s);
    }
    wacc = fmaf(gpre[tt], fmaf(-0.5f, s, -ld4), wacc);
  }

#pragma unroll
  for (int off = 1; off < 64; off <<= 1) wacc += __shfl_xor(wacc, off);
  if (lane == 0) solve_part[blockIdx.x] = wacc;
}

// Deterministic reduce + distinct-subject count + final combine.
__global__ __launch_bounds__(256) void finalize_kernel(
    const float* __restrict__ solve_part, const float* __restrict__ mu_part,
    const float* __restrict__ L_part, const int* __restrict__ sids,
    float* __restrict__ out) {
  __shared__ int ssv[32];
  __shared__ double r0[4], r1[4], r2[4];
  __shared__ int r3[4];
  int tid = threadIdx.x;
  if (tid < 32) ssv[tid] = sids[tid];
  __syncthreads();

  double s_ll = 0.0, s_mu = 0.0, s_L = 0.0;
  for (int i = tid; i < MFMA_BLOCKS; i += 256) s_ll += (double)solve_part[i];
  for (int i = tid; i < REG_BLOCKS; i += 256) {
    s_mu += (double)mu_part[i];
    s_L += (double)L_part[i];
  }
  int cnt = 0;
  if (tid < NS) {
    for (int i = 0; i < 32; ++i)
      if (ssv[i] == tid) { cnt = 1; break; }
  }
#pragma unroll
  for (int off = 1; off < 64; off <<= 1) {
    s_ll += __shfl_xor(s_ll, off);
    s_mu += __shfl_xor(s_mu, off);
    s_L += __shfl_xor(s_L, off);
    cnt += __shfl_xor(cnt, off);
  }
  int lane = tid & 63;
  if (lane == 0) {
    r0[tid >> 6] = s_ll;
    r1[tid >> 6] = s_mu;
    r2[tid >> 6] = s_L;
    r3[tid >> 6] = cnt;
  }
  __syncthreads();
  if (tid == 0) {
    double ll_sum = r0[0] + r0[1] + r0[2] + r0[3];
    double mu_reg = r1[0] + r1[1] + r1[2] + r1[3];
    double L_reg = r2[0] + r2[1] + r2[2] + r2[3];
    int c = r3[0] + r3[1] + r3[2] + r3[3];
    double c0 = 0.5 * (double)NC * log(2.0 * M_PI);
    double ll = ll_sum / (double)NB - (double)NT * c0;
    double reg = (0.5 * mu_reg + 0.5 * L_reg) * ((double)c / (double)NS);
    out[0] = (float)(-ll + reg);
  }
}

extern "C" void kernel_launch(void* const* d_in, const int* in_sizes, int n_in,
                              void* d_out, int out_size, void* d_ws,
                              size_t ws_size, hipStream_t stream) {
  const float* data    = (const float*)d_in[0];
  const float* mu_pop  = (const float*)d_in[1];
  const float* L_pop   = (const float*)d_in[2];
  const float* mu_subj = (const float*)d_in[3];
  const float* L_subj  = (const float*)d_in[4];
  const float* gamma   = (const float*)d_in[5];
  const int*   sids    = (const int*)d_in[6];
  float* out = (float*)d_out;

  unsigned short* Wws = (unsigned short*)d_ws;  // 3 MB
  float* ldws       = (float*)((char*)d_ws + (size_t)INV_BLOCKS * NC * NC * 2);
  float* solve_part = ldws + INV_BLOCKS;
  float* mu_part    = solve_part + MFMA_BLOCKS;
  float* L_part     = mu_part + REG_BLOCKS;

  hipLaunchKernelGGL(prep_kernel, dim3(PREP_BLOCKS), dim3(256), 0, stream,
                     mu_pop, L_pop, mu_subj, L_subj, sids, Wws, ldws, mu_part,
                     L_part);
  hipLaunchKernelGGL(mfma_kernel, dim3(MFMA_BLOCKS), dim3(64), 0, stream,
                     data, mu_subj, gamma, sids, Wws, ldws, solve_part);
  hipLaunchKernelGGL(finalize_kernel, dim3(1), dim3(256), 0, stream,
                     solve_part, mu_part, L_part, sids, out);
}